// Round 1
// baseline (1911.267 us; speedup 1.0000x reference)
//
#include <hip/hip_runtime.h>

// Problem dims (fixed by the reference)
#define T_TOK 2048      // B*S tokens
#define H_DIM 2048
#define E_NUM 32
#define I_DIM 1024
#define IS_DIM 2048
#define K_TOT (E_NUM * I_DIM + IS_DIM)   // 34816 = routed(32768) + shared(2048)

typedef __bf16 bf16x8 __attribute__((ext_vector_type(8)));
typedef float  f32x4  __attribute__((ext_vector_type(4)));
static_assert(sizeof(bf16x8) == 16, "bf16x8 must be 16B");

// Workspace layout (bytes). Total = 579,076,096 (~552 MiB).
#define OFF_DW    ((size_t)0)           // dense_w  [T,E] fp32          262,144
#define OFF_XB    ((size_t)262144)      // xb       [T,H] bf16        8,388,608
#define OFF_WGT   ((size_t)8650752)     // wgT [E][I][H] bf16       134,217,728
#define OFF_WUT   ((size_t)142868480)   // wuT [E][I][H] bf16       134,217,728
#define OFF_WSGT  ((size_t)277086208)   // wsgT [IS][H] bf16          8,388,608
#define OFF_WSUT  ((size_t)285474816)   // wsuT [IS][H] bf16          8,388,608
#define OFF_WDT   ((size_t)293863424)   // wdT [H][K_TOT] bf16      142,606,336
#define OFF_H     ((size_t)436469760)   // h   [T][K_TOT] bf16      142,606,336

__device__ __forceinline__ unsigned short f2bf(float f) {
  unsigned int u = __float_as_uint(f);
  u += 0x7fffu + ((u >> 16) & 1u);   // round-to-nearest-even
  return (unsigned short)(u >> 16);
}

__device__ __forceinline__ void gld16(const void* g, void* l) {
  __builtin_amdgcn_global_load_lds(
      (const __attribute__((address_space(1))) unsigned int*)g,
      (__attribute__((address_space(3))) unsigned int*)l, 16, 0, 0);
}

// ---------------------------------------------------------------------------
// Router: scores = sigmoid(x @ gw^T); top-8; renorm; *2.5 -> dense_w [T,E]
// ---------------------------------------------------------------------------
__global__ __launch_bounds__(256) void router_kernel(
    const float* __restrict__ x, const float* __restrict__ gw,
    float* __restrict__ dense_w)
{
  const int t = blockIdx.x;
  __shared__ float xs[H_DIM];
  __shared__ float sc[E_NUM];
  const float4* xr = (const float4*)(x + (long)t * H_DIM);
  for (int i = threadIdx.x; i < H_DIM / 4; i += 256) ((float4*)xs)[i] = xr[i];
  __syncthreads();
  const int e = threadIdx.x >> 3, p = threadIdx.x & 7;
  const float4* ga = (const float4*)(gw + (long)e * H_DIM);
  const float4* xa = (const float4*)xs;
  float s = 0.f;
  #pragma unroll 4
  for (int i = p * 64; i < p * 64 + 64; ++i) {
    float4 a = ga[i], b = xa[i];
    s += a.x * b.x + a.y * b.y + a.z * b.z + a.w * b.w;
  }
  s += __shfl_down(s, 4, 8);
  s += __shfl_down(s, 2, 8);
  s += __shfl_down(s, 1, 8);
  if (p == 0) sc[e] = 1.f / (1.f + expf(-s));
  __syncthreads();
  if (threadIdx.x == 0) {
    float v[E_NUM];
    #pragma unroll
    for (int i = 0; i < E_NUM; ++i) v[i] = sc[i];
    unsigned mask = 0; float sum = 0.f;
    int sel[8]; float wv[8];
    for (int k = 0; k < 8; ++k) {
      float best = -1.f; int bi = 0;
      for (int i = 0; i < E_NUM; ++i)
        if (!((mask >> i) & 1u) && v[i] > best) { best = v[i]; bi = i; }
      mask |= 1u << bi; sel[k] = bi; wv[k] = best; sum += best;
    }
    const float scale = 2.5f / (sum + 1e-20f);
    float outv[E_NUM];
    #pragma unroll
    for (int i = 0; i < E_NUM; ++i) outv[i] = 0.f;
    for (int k = 0; k < 8; ++k) outv[sel[k]] = wv[k] * scale;
    float* dr = dense_w + (long)t * E_NUM;
    #pragma unroll
    for (int i = 0; i < E_NUM; ++i) dr[i] = outv[i];
  }
}

// ---------------------------------------------------------------------------
// fp32 -> bf16 elementwise (x -> xb)
// ---------------------------------------------------------------------------
__global__ __launch_bounds__(256) void cvt_bf16_kernel(
    const float* __restrict__ in, unsigned short* __restrict__ out, int n4)
{
  int i = blockIdx.x * 256 + threadIdx.x;
  if (i >= n4) return;
  float4 v = ((const float4*)in)[i];
  ushort4 o;
  o.x = f2bf(v.x); o.y = f2bf(v.y); o.z = f2bf(v.z); o.w = f2bf(v.w);
  ((ushort4*)out)[i] = o;
}

// ---------------------------------------------------------------------------
// Transpose + fp32->bf16: in fp32 [R][C] (row-major, ldin=C) -> out bf16 [C][R]
// with out row stride ldout; batched over blockIdx.z.
// ---------------------------------------------------------------------------
__global__ __launch_bounds__(256) void transpose_cvt(
    const float* __restrict__ in, unsigned short* __restrict__ out,
    int R, int C, int ldout, long in_bs, long out_bs)
{
  in  += (long)blockIdx.z * in_bs;
  out += (long)blockIdx.z * out_bs;
  __shared__ float tile[64][65];
  const int c0 = blockIdx.x * 64;
  const int r0 = blockIdx.y * 64;
  const int t = threadIdx.x;
  const int lr = t >> 4;
  const int lc = (t & 15) << 2;
  #pragma unroll
  for (int rr = 0; rr < 64; rr += 16) {
    float4 v = *(const float4*)(in + (long)(r0 + lr + rr) * C + c0 + lc);
    tile[lr + rr][lc + 0] = v.x;
    tile[lr + rr][lc + 1] = v.y;
    tile[lr + rr][lc + 2] = v.z;
    tile[lr + rr][lc + 3] = v.w;
  }
  __syncthreads();
  #pragma unroll
  for (int rr = 0; rr < 64; rr += 16) {
    const int c = c0 + lr + rr;
    ushort4 o;
    o.x = f2bf(tile[lc + 0][lr + rr]);
    o.y = f2bf(tile[lc + 1][lr + rr]);
    o.z = f2bf(tile[lc + 2][lr + rr]);
    o.w = f2bf(tile[lc + 3][lr + rr]);
    *(ushort4*)(out + (long)c * ldout + r0 + lc) = o;
  }
}

// ---------------------------------------------------------------------------
// Fused gate+up GEMM (m97-style bt-GEMM, dual B) + silu(g)*u*dense_w epilogue.
// A = xb [T,H] bf16; Bg/Bu = [nb][N][H] bf16 (pre-transposed).
// h[t, col_off + z*Ncols + n] = bf16( silu(g)*u * w ), w = dense_w[t,z] or 1.
// Block: 256 thr (4 waves 2x2), tile 128(M) x 64(N), BK=64.
// ---------------------------------------------------------------------------
__global__ __launch_bounds__(256) void gate_up_kernel(
    const unsigned short* __restrict__ xb,
    const unsigned short* __restrict__ bgT,
    const unsigned short* __restrict__ buT,
    const float* __restrict__ dw,
    unsigned short* __restrict__ hout,
    int Ncols, int col_off)
{
  const int t0 = blockIdx.x * 128;
  const int n0 = blockIdx.y * 64;
  const int e  = blockIdx.z;
  const long bstr = (long)Ncols * H_DIM;
  const unsigned short* Bg = bgT + e * bstr + (long)n0 * H_DIM;
  const unsigned short* Bu = buT + e * bstr + (long)n0 * H_DIM;
  const unsigned short* A  = xb + (long)t0 * H_DIM;

  __shared__ unsigned short sA[128 * 64];
  __shared__ unsigned short sBg[64 * 64];
  __shared__ unsigned short sBu[64 * 64];

  const int tid = threadIdx.x;
  const int lane = tid & 63;
  const int wid = tid >> 6;
  const int wm = wid >> 1, wn = wid & 1;
  const int l15 = lane & 15;
  const int lk  = (lane >> 4) * 8;
  const int srow = tid >> 3;
  const int scol = (tid & 7) * 8;

  const f32x4 fz = {0.f, 0.f, 0.f, 0.f};
  f32x4 accg[4][2], accu[4][2];
  #pragma unroll
  for (int i = 0; i < 4; ++i)
    #pragma unroll
    for (int j = 0; j < 2; ++j) { accg[i][j] = fz; accu[i][j] = fz; }

  for (int k0 = 0; k0 < H_DIM; k0 += 64) {
    #pragma unroll
    for (int r = 0; r < 4; ++r)
      gld16(A + (long)(r * 32 + srow) * H_DIM + k0 + scol,
            sA + (r * 32 + srow) * 64 + scol);
    #pragma unroll
    for (int r = 0; r < 2; ++r) {
      gld16(Bg + (long)(r * 32 + srow) * H_DIM + k0 + scol,
            sBg + (r * 32 + srow) * 64 + scol);
      gld16(Bu + (long)(r * 32 + srow) * H_DIM + k0 + scol,
            sBu + (r * 32 + srow) * 64 + scol);
    }
    __syncthreads();
    #pragma unroll
    for (int kk = 0; kk < 2; ++kk) {
      const int ko = kk * 32 + lk;
      bf16x8 a[4], g[2], u[2];
      #pragma unroll
      for (int mi = 0; mi < 4; ++mi)
        a[mi] = *(const bf16x8*)(sA + (wm * 64 + mi * 16 + l15) * 64 + ko);
      #pragma unroll
      for (int ni = 0; ni < 2; ++ni) {
        g[ni] = *(const bf16x8*)(sBg + (wn * 32 + ni * 16 + l15) * 64 + ko);
        u[ni] = *(const bf16x8*)(sBu + (wn * 32 + ni * 16 + l15) * 64 + ko);
      }
      #pragma unroll
      for (int mi = 0; mi < 4; ++mi)
        #pragma unroll
        for (int ni = 0; ni < 2; ++ni) {
          accg[mi][ni] = __builtin_amdgcn_mfma_f32_16x16x32_bf16(a[mi], g[ni], accg[mi][ni], 0, 0, 0);
          accu[mi][ni] = __builtin_amdgcn_mfma_f32_16x16x32_bf16(a[mi], u[ni], accu[mi][ni], 0, 0, 0);
        }
    }
    __syncthreads();
  }

  const bool hasdw = (dw != nullptr);
  const int colb = col_off + e * Ncols + n0 + wn * 32;
  #pragma unroll
  for (int mi = 0; mi < 4; ++mi) {
    #pragma unroll
    for (int r = 0; r < 4; ++r) {
      const int t = t0 + wm * 64 + mi * 16 + (lane >> 4) * 4 + r;
      const float w = hasdw ? dw[(long)t * E_NUM + e] : 1.f;
      #pragma unroll
      for (int ni = 0; ni < 2; ++ni) {
        const float gv = accg[mi][ni][r];
        const float uv = accu[mi][ni][r];
        const float sv = (gv / (1.f + expf(-gv))) * uv * w;
        hout[(long)t * K_TOT + colb + ni * 16 + l15] = f2bf(sv);
      }
    }
  }
}

// ---------------------------------------------------------------------------
// Down GEMM + combine: out[T,H] = h[T,K_TOT] @ wdT^T  (wdT is [H][K_TOT] bf16)
// Block: 256 thr, tile 128(M) x 64(N), BK=64; fp32 output.
// ---------------------------------------------------------------------------
__global__ __launch_bounds__(256) void down_kernel(
    const unsigned short* __restrict__ hbuf,
    const unsigned short* __restrict__ wdT,
    float* __restrict__ out)
{
  const int t0 = blockIdx.x * 128;
  const int n0 = blockIdx.y * 64;
  const unsigned short* A = hbuf + (long)t0 * K_TOT;
  const unsigned short* B = wdT + (long)n0 * K_TOT;

  __shared__ unsigned short sA[128 * 64];
  __shared__ unsigned short sB[64 * 64];

  const int tid = threadIdx.x;
  const int lane = tid & 63;
  const int wid = tid >> 6;
  const int wm = wid >> 1, wn = wid & 1;
  const int l15 = lane & 15;
  const int lk  = (lane >> 4) * 8;
  const int srow = tid >> 3;
  const int scol = (tid & 7) * 8;

  const f32x4 fz = {0.f, 0.f, 0.f, 0.f};
  f32x4 acc[4][2];
  #pragma unroll
  for (int i = 0; i < 4; ++i)
    #pragma unroll
    for (int j = 0; j < 2; ++j) acc[i][j] = fz;

  for (long k0 = 0; k0 < K_TOT; k0 += 64) {
    #pragma unroll
    for (int r = 0; r < 4; ++r)
      gld16(A + (long)(r * 32 + srow) * K_TOT + k0 + scol,
            sA + (r * 32 + srow) * 64 + scol);
    #pragma unroll
    for (int r = 0; r < 2; ++r)
      gld16(B + (long)(r * 32 + srow) * K_TOT + k0 + scol,
            sB + (r * 32 + srow) * 64 + scol);
    __syncthreads();
    #pragma unroll
    for (int kk = 0; kk < 2; ++kk) {
      const int ko = kk * 32 + lk;
      bf16x8 a[4], b[2];
      #pragma unroll
      for (int mi = 0; mi < 4; ++mi)
        a[mi] = *(const bf16x8*)(sA + (wm * 64 + mi * 16 + l15) * 64 + ko);
      #pragma unroll
      for (int ni = 0; ni < 2; ++ni)
        b[ni] = *(const bf16x8*)(sB + (wn * 32 + ni * 16 + l15) * 64 + ko);
      #pragma unroll
      for (int mi = 0; mi < 4; ++mi)
        #pragma unroll
        for (int ni = 0; ni < 2; ++ni)
          acc[mi][ni] = __builtin_amdgcn_mfma_f32_16x16x32_bf16(a[mi], b[ni], acc[mi][ni], 0, 0, 0);
    }
    __syncthreads();
  }

  #pragma unroll
  for (int mi = 0; mi < 4; ++mi) {
    #pragma unroll
    for (int r = 0; r < 4; ++r) {
      const int t = t0 + wm * 64 + mi * 16 + (lane >> 4) * 4 + r;
      #pragma unroll
      for (int ni = 0; ni < 2; ++ni) {
        const int col = n0 + wn * 32 + ni * 16 + l15;
        out[(long)t * H_DIM + col] = acc[mi][ni][r];
      }
    }
  }
}

// ---------------------------------------------------------------------------
extern "C" void kernel_launch(void* const* d_in, const int* in_sizes, int n_in,
                              void* d_out, int out_size, void* d_ws, size_t ws_size,
                              hipStream_t stream) {
  (void)in_sizes; (void)n_in; (void)out_size; (void)ws_size;
  const float* x   = (const float*)d_in[0];
  const float* gw  = (const float*)d_in[1];
  const float* wg  = (const float*)d_in[2];
  const float* wu  = (const float*)d_in[3];
  const float* wd  = (const float*)d_in[4];
  const float* wsg = (const float*)d_in[5];
  const float* wsu = (const float*)d_in[6];
  const float* wsd = (const float*)d_in[7];
  float* out = (float*)d_out;
  char* ws = (char*)d_ws;

  float*          dense_w = (float*)(ws + OFF_DW);
  unsigned short* xb      = (unsigned short*)(ws + OFF_XB);
  unsigned short* wgT     = (unsigned short*)(ws + OFF_WGT);
  unsigned short* wuT     = (unsigned short*)(ws + OFF_WUT);
  unsigned short* wsgT    = (unsigned short*)(ws + OFF_WSGT);
  unsigned short* wsuT    = (unsigned short*)(ws + OFF_WSUT);
  unsigned short* wdT     = (unsigned short*)(ws + OFF_WDT);
  unsigned short* hbuf    = (unsigned short*)(ws + OFF_H);

  // router + activation convert
  router_kernel<<<T_TOK, 256, 0, stream>>>(x, gw, dense_w);
  cvt_bf16_kernel<<<(T_TOK * H_DIM / 4 + 255) / 256, 256, 0, stream>>>(
      x, xb, T_TOK * H_DIM / 4);

  // weight transpose + bf16 convert
  transpose_cvt<<<dim3(16, 32, 32), 256, 0, stream>>>(
      wg, wgT, H_DIM, I_DIM, H_DIM, (long)H_DIM * I_DIM, (long)I_DIM * H_DIM);
  transpose_cvt<<<dim3(16, 32, 32), 256, 0, stream>>>(
      wu, wuT, H_DIM, I_DIM, H_DIM, (long)H_DIM * I_DIM, (long)I_DIM * H_DIM);
  transpose_cvt<<<dim3(32, 16, 32), 256, 0, stream>>>(
      wd, wdT, I_DIM, H_DIM, K_TOT, (long)I_DIM * H_DIM, (long)I_DIM);
  transpose_cvt<<<dim3(32, 32, 1), 256, 0, stream>>>(
      wsg, wsgT, H_DIM, IS_DIM, H_DIM, 0, 0);
  transpose_cvt<<<dim3(32, 32, 1), 256, 0, stream>>>(
      wsu, wsuT, H_DIM, IS_DIM, H_DIM, 0, 0);
  transpose_cvt<<<dim3(32, 32, 1), 256, 0, stream>>>(
      wsd, wdT + E_NUM * I_DIM, IS_DIM, H_DIM, K_TOT, 0, 0);

  // experts gate+up (dense_w folded in), then shared gate+up (weight 1)
  gate_up_kernel<<<dim3(16, 16, 32), 256, 0, stream>>>(
      xb, wgT, wuT, dense_w, hbuf, I_DIM, 0);
  gate_up_kernel<<<dim3(16, 32, 1), 256, 0, stream>>>(
      xb, wsgT, wsuT, nullptr, hbuf, IS_DIM, E_NUM * I_DIM);

  // single fused down-proj + combine + shared-down
  down_kernel<<<dim3(16, 32), 256, 0, stream>>>(hbuf, wdT, out);
}

// Round 2
// 1503.922 us; speedup vs baseline: 1.2709x; 1.2709x over previous
//
#include <hip/hip_runtime.h>

// Problem dims (fixed by the reference)
#define T_TOK 2048      // B*S tokens
#define H_DIM 2048
#define E_NUM 32
#define I_DIM 1024
#define IS_DIM 2048
#define K_TOT (E_NUM * I_DIM + IS_DIM)   // 34816 = routed(32768) + shared(2048)

typedef __bf16 bf16x8 __attribute__((ext_vector_type(8)));
typedef float  f32x4  __attribute__((ext_vector_type(4)));
static_assert(sizeof(bf16x8) == 16, "bf16x8 must be 16B");

// Workspace layout (bytes). Total = 579,076,096 (~552 MiB).
#define OFF_DW    ((size_t)0)           // dense_w  [T,E] fp32          262,144
#define OFF_XB    ((size_t)262144)      // xb       [T,H] bf16        8,388,608
#define OFF_WGT   ((size_t)8650752)     // wgT [E][I][H] bf16       134,217,728
#define OFF_WUT   ((size_t)142868480)   // wuT [E][I][H] bf16       134,217,728
#define OFF_WSGT  ((size_t)277086208)   // wsgT [IS][H] bf16          8,388,608
#define OFF_WSUT  ((size_t)285474816)   // wsuT [IS][H] bf16          8,388,608
#define OFF_WDT   ((size_t)293863424)   // wdT [H][K_TOT] bf16      142,606,336
#define OFF_H     ((size_t)436469760)   // h   [T][K_TOT] bf16      142,606,336

__device__ __forceinline__ unsigned short f2bf(float f) {
  unsigned int u = __float_as_uint(f);
  u += 0x7fffu + ((u >> 16) & 1u);   // round-to-nearest-even
  return (unsigned short)(u >> 16);
}

__device__ __forceinline__ void gld16(const void* g, void* l) {
  __builtin_amdgcn_global_load_lds(
      (const __attribute__((address_space(1))) unsigned int*)g,
      (__attribute__((address_space(3))) unsigned int*)l, 16, 0, 0);
}

// ---------------------------------------------------------------------------
// Router: scores = sigmoid(x @ gw^T); top-8; renorm; *2.5 -> dense_w [T,E]
// ---------------------------------------------------------------------------
__global__ __launch_bounds__(256) void router_kernel(
    const float* __restrict__ x, const float* __restrict__ gw,
    float* __restrict__ dense_w)
{
  const int t = blockIdx.x;
  __shared__ float xs[H_DIM];
  __shared__ float sc[E_NUM];
  const float4* xr = (const float4*)(x + (long)t * H_DIM);
  for (int i = threadIdx.x; i < H_DIM / 4; i += 256) ((float4*)xs)[i] = xr[i];
  __syncthreads();
  const int e = threadIdx.x >> 3, p = threadIdx.x & 7;
  const float4* ga = (const float4*)(gw + (long)e * H_DIM);
  const float4* xa = (const float4*)xs;
  float s = 0.f;
  #pragma unroll 4
  for (int i = p * 64; i < p * 64 + 64; ++i) {
    float4 a = ga[i], b = xa[i];
    s += a.x * b.x + a.y * b.y + a.z * b.z + a.w * b.w;
  }
  s += __shfl_down(s, 4, 8);
  s += __shfl_down(s, 2, 8);
  s += __shfl_down(s, 1, 8);
  if (p == 0) sc[e] = 1.f / (1.f + expf(-s));
  __syncthreads();
  if (threadIdx.x == 0) {
    float v[E_NUM];
    #pragma unroll
    for (int i = 0; i < E_NUM; ++i) v[i] = sc[i];
    unsigned mask = 0; float sum = 0.f;
    int sel[8]; float wv[8];
    for (int k = 0; k < 8; ++k) {
      float best = -1.f; int bi = 0;
      for (int i = 0; i < E_NUM; ++i)
        if (!((mask >> i) & 1u) && v[i] > best) { best = v[i]; bi = i; }
      mask |= 1u << bi; sel[k] = bi; wv[k] = best; sum += best;
    }
    const float scale = 2.5f / (sum + 1e-20f);
    float outv[E_NUM];
    #pragma unroll
    for (int i = 0; i < E_NUM; ++i) outv[i] = 0.f;
    for (int k = 0; k < 8; ++k) outv[sel[k]] = wv[k] * scale;
    float* dr = dense_w + (long)t * E_NUM;
    #pragma unroll
    for (int i = 0; i < E_NUM; ++i) dr[i] = outv[i];
  }
}

// ---------------------------------------------------------------------------
// fp32 -> bf16 elementwise (x -> xb)
// ---------------------------------------------------------------------------
__global__ __launch_bounds__(256) void cvt_bf16_kernel(
    const float* __restrict__ in, unsigned short* __restrict__ out, int n4)
{
  int i = blockIdx.x * 256 + threadIdx.x;
  if (i >= n4) return;
  float4 v = ((const float4*)in)[i];
  ushort4 o;
  o.x = f2bf(v.x); o.y = f2bf(v.y); o.z = f2bf(v.z); o.w = f2bf(v.w);
  ((ushort4*)out)[i] = o;
}

// ---------------------------------------------------------------------------
// Transpose + fp32->bf16: in fp32 [R][C] (row-major, ldin=C) -> out bf16 [C][R]
// with out row stride ldout; batched over blockIdx.z.
// ---------------------------------------------------------------------------
__global__ __launch_bounds__(256) void transpose_cvt(
    const float* __restrict__ in, unsigned short* __restrict__ out,
    int R, int C, int ldout, long in_bs, long out_bs)
{
  in  += (long)blockIdx.z * in_bs;
  out += (long)blockIdx.z * out_bs;
  __shared__ float tile[64][65];
  const int c0 = blockIdx.x * 64;
  const int r0 = blockIdx.y * 64;
  const int t = threadIdx.x;
  const int lr = t >> 4;
  const int lc = (t & 15) << 2;
  #pragma unroll
  for (int rr = 0; rr < 64; rr += 16) {
    float4 v = *(const float4*)(in + (long)(r0 + lr + rr) * C + c0 + lc);
    tile[lr + rr][lc + 0] = v.x;
    tile[lr + rr][lc + 1] = v.y;
    tile[lr + rr][lc + 2] = v.z;
    tile[lr + rr][lc + 3] = v.w;
  }
  __syncthreads();
  #pragma unroll
  for (int rr = 0; rr < 64; rr += 16) {
    const int c = c0 + lr + rr;
    ushort4 o;
    o.x = f2bf(tile[lc + 0][lr + rr]);
    o.y = f2bf(tile[lc + 1][lr + rr]);
    o.z = f2bf(tile[lc + 2][lr + rr]);
    o.w = f2bf(tile[lc + 3][lr + rr]);
    *(ushort4*)(out + (long)c * ldout + r0 + lc) = o;
  }
}

// ---------------------------------------------------------------------------
// Fused gate+up GEMM (m97-style bt-GEMM, dual B) + silu(g)*u*dense_w epilogue.
// A = xb [T,H] bf16; Bg/Bu = [nb][N][H] bf16 (pre-transposed).
// h[t, col_off + z*Ncols + n] = bf16( silu(g)*u * w ), w = dense_w[t,z] or 1.
// Block: 256 thr (4 waves 2x2), tile 128(M) x 64(N), BK=64.
// LDS tiles XOR-swizzled (T2 via m173): chunk c of row r lives at LDS chunk
// c ^ (r&7); global_load_lds dest stays LINEAR, global SOURCE is pre-permuted.
// ---------------------------------------------------------------------------
__global__ __launch_bounds__(256) void gate_up_kernel(
    const unsigned short* __restrict__ xb,
    const unsigned short* __restrict__ bgT,
    const unsigned short* __restrict__ buT,
    const float* __restrict__ dw,
    unsigned short* __restrict__ hout,
    int Ncols, int col_off)
{
  const int t0 = blockIdx.x * 128;
  const int n0 = blockIdx.y * 64;
  const int e  = blockIdx.z;
  const long bstr = (long)Ncols * H_DIM;
  const unsigned short* Bg = bgT + e * bstr + (long)n0 * H_DIM;
  const unsigned short* Bu = buT + e * bstr + (long)n0 * H_DIM;
  const unsigned short* A  = xb + (long)t0 * H_DIM;

  __shared__ unsigned short sA[128 * 64];
  __shared__ unsigned short sBg[64 * 64];
  __shared__ unsigned short sBu[64 * 64];

  const int tid = threadIdx.x;
  const int lane = tid & 63;
  const int wid = tid >> 6;
  const int wm = wid >> 1, wn = wid & 1;
  const int l15 = lane & 15;
  const int lk  = (lane >> 4) * 8;
  const int srow = tid >> 3;                       // LDS row within 32-row group
  const int scol = (tid & 7) * 8;                  // linear LDS dest chunk (bf16)
  // pre-swizzled SOURCE chunk: LDS chunk (tid&7) must hold src chunk (tid&7)^(row&7)
  const int scolsw = (((tid & 7) ^ ((tid >> 3) & 7))) * 8;
  const int ksw = (l15 & 7) << 3;                  // read-side XOR (bf16 units)

  const f32x4 fz = {0.f, 0.f, 0.f, 0.f};
  f32x4 accg[4][2], accu[4][2];
  #pragma unroll
  for (int i = 0; i < 4; ++i)
    #pragma unroll
    for (int j = 0; j < 2; ++j) { accg[i][j] = fz; accu[i][j] = fz; }

  for (int k0 = 0; k0 < H_DIM; k0 += 64) {
    #pragma unroll
    for (int r = 0; r < 4; ++r)
      gld16(A + (long)(r * 32 + srow) * H_DIM + k0 + scolsw,
            sA + (r * 32 + srow) * 64 + scol);
    #pragma unroll
    for (int r = 0; r < 2; ++r) {
      gld16(Bg + (long)(r * 32 + srow) * H_DIM + k0 + scolsw,
            sBg + (r * 32 + srow) * 64 + scol);
      gld16(Bu + (long)(r * 32 + srow) * H_DIM + k0 + scolsw,
            sBu + (r * 32 + srow) * 64 + scol);
    }
    __syncthreads();
    #pragma unroll
    for (int kk = 0; kk < 2; ++kk) {
      const int ko = kk * 32 + lk;
      bf16x8 a[4], g[2], u[2];
      #pragma unroll
      for (int mi = 0; mi < 4; ++mi)
        a[mi] = *(const bf16x8*)(sA + (wm * 64 + mi * 16 + l15) * 64 + (ko ^ ksw));
      #pragma unroll
      for (int ni = 0; ni < 2; ++ni) {
        g[ni] = *(const bf16x8*)(sBg + (wn * 32 + ni * 16 + l15) * 64 + (ko ^ ksw));
        u[ni] = *(const bf16x8*)(sBu + (wn * 32 + ni * 16 + l15) * 64 + (ko ^ ksw));
      }
      #pragma unroll
      for (int mi = 0; mi < 4; ++mi)
        #pragma unroll
        for (int ni = 0; ni < 2; ++ni) {
          accg[mi][ni] = __builtin_amdgcn_mfma_f32_16x16x32_bf16(a[mi], g[ni], accg[mi][ni], 0, 0, 0);
          accu[mi][ni] = __builtin_amdgcn_mfma_f32_16x16x32_bf16(a[mi], u[ni], accu[mi][ni], 0, 0, 0);
        }
    }
    __syncthreads();
  }

  const bool hasdw = (dw != nullptr);
  const int colb = col_off + e * Ncols + n0 + wn * 32;
  #pragma unroll
  for (int mi = 0; mi < 4; ++mi) {
    #pragma unroll
    for (int r = 0; r < 4; ++r) {
      const int t = t0 + wm * 64 + mi * 16 + (lane >> 4) * 4 + r;
      const float w = hasdw ? dw[(long)t * E_NUM + e] : 1.f;
      #pragma unroll
      for (int ni = 0; ni < 2; ++ni) {
        const float gv = accg[mi][ni][r];
        const float uv = accu[mi][ni][r];
        const float sv = (gv / (1.f + expf(-gv))) * uv * w;
        hout[(long)t * K_TOT + colb + ni * 16 + l15] = f2bf(sv);
      }
    }
  }
}

// ---------------------------------------------------------------------------
// Down GEMM + combine: out[T,H] = h[T,K_TOT] @ wdT^T  (wdT is [H][K_TOT] bf16)
// Block: 256 thr, tile 128(M) x 64(N), BK=64; fp32 output. Same XOR swizzle.
// ---------------------------------------------------------------------------
__global__ __launch_bounds__(256) void down_kernel(
    const unsigned short* __restrict__ hbuf,
    const unsigned short* __restrict__ wdT,
    float* __restrict__ out)
{
  const int t0 = blockIdx.x * 128;
  const int n0 = blockIdx.y * 64;
  const unsigned short* A = hbuf + (long)t0 * K_TOT;
  const unsigned short* B = wdT + (long)n0 * K_TOT;

  __shared__ unsigned short sA[128 * 64];
  __shared__ unsigned short sB[64 * 64];

  const int tid = threadIdx.x;
  const int lane = tid & 63;
  const int wid = tid >> 6;
  const int wm = wid >> 1, wn = wid & 1;
  const int l15 = lane & 15;
  const int lk  = (lane >> 4) * 8;
  const int srow = tid >> 3;
  const int scol = (tid & 7) * 8;
  const int scolsw = (((tid & 7) ^ ((tid >> 3) & 7))) * 8;
  const int ksw = (l15 & 7) << 3;

  const f32x4 fz = {0.f, 0.f, 0.f, 0.f};
  f32x4 acc[4][2];
  #pragma unroll
  for (int i = 0; i < 4; ++i)
    #pragma unroll
    for (int j = 0; j < 2; ++j) acc[i][j] = fz;

  for (long k0 = 0; k0 < K_TOT; k0 += 64) {
    #pragma unroll
    for (int r = 0; r < 4; ++r)
      gld16(A + (long)(r * 32 + srow) * K_TOT + k0 + scolsw,
            sA + (r * 32 + srow) * 64 + scol);
    #pragma unroll
    for (int r = 0; r < 2; ++r)
      gld16(B + (long)(r * 32 + srow) * K_TOT + k0 + scolsw,
            sB + (r * 32 + srow) * 64 + scol);
    __syncthreads();
    #pragma unroll
    for (int kk = 0; kk < 2; ++kk) {
      const int ko = kk * 32 + lk;
      bf16x8 a[4], b[2];
      #pragma unroll
      for (int mi = 0; mi < 4; ++mi)
        a[mi] = *(const bf16x8*)(sA + (wm * 64 + mi * 16 + l15) * 64 + (ko ^ ksw));
      #pragma unroll
      for (int ni = 0; ni < 2; ++ni)
        b[ni] = *(const bf16x8*)(sB + (wn * 32 + ni * 16 + l15) * 64 + (ko ^ ksw));
      #pragma unroll
      for (int mi = 0; mi < 4; ++mi)
        #pragma unroll
        for (int ni = 0; ni < 2; ++ni)
          acc[mi][ni] = __builtin_amdgcn_mfma_f32_16x16x32_bf16(a[mi], b[ni], acc[mi][ni], 0, 0, 0);
    }
    __syncthreads();
  }

  #pragma unroll
  for (int mi = 0; mi < 4; ++mi) {
    #pragma unroll
    for (int r = 0; r < 4; ++r) {
      const int t = t0 + wm * 64 + mi * 16 + (lane >> 4) * 4 + r;
      #pragma unroll
      for (int ni = 0; ni < 2; ++ni) {
        const int col = n0 + wn * 32 + ni * 16 + l15;
        out[(long)t * H_DIM + col] = acc[mi][ni][r];
      }
    }
  }
}

// ---------------------------------------------------------------------------
extern "C" void kernel_launch(void* const* d_in, const int* in_sizes, int n_in,
                              void* d_out, int out_size, void* d_ws, size_t ws_size,
                              hipStream_t stream) {
  (void)in_sizes; (void)n_in; (void)out_size; (void)ws_size;
  const float* x   = (const float*)d_in[0];
  const float* gw  = (const float*)d_in[1];
  const float* wg  = (const float*)d_in[2];
  const float* wu  = (const float*)d_in[3];
  const float* wd  = (const float*)d_in[4];
  const float* wsg = (const float*)d_in[5];
  const float* wsu = (const float*)d_in[6];
  const float* wsd = (const float*)d_in[7];
  float* out = (float*)d_out;
  char* ws = (char*)d_ws;

  float*          dense_w = (float*)(ws + OFF_DW);
  unsigned short* xb      = (unsigned short*)(ws + OFF_XB);
  unsigned short* wgT     = (unsigned short*)(ws + OFF_WGT);
  unsigned short* wuT     = (unsigned short*)(ws + OFF_WUT);
  unsigned short* wsgT    = (unsigned short*)(ws + OFF_WSGT);
  unsigned short* wsuT    = (unsigned short*)(ws + OFF_WSUT);
  unsigned short* wdT     = (unsigned short*)(ws + OFF_WDT);
  unsigned short* hbuf    = (unsigned short*)(ws + OFF_H);

  // router + activation convert
  router_kernel<<<T_TOK, 256, 0, stream>>>(x, gw, dense_w);
  cvt_bf16_kernel<<<(T_TOK * H_DIM / 4 + 255) / 256, 256, 0, stream>>>(
      x, xb, T_TOK * H_DIM / 4);

  // weight transpose + bf16 convert
  transpose_cvt<<<dim3(16, 32, 32), 256, 0, stream>>>(
      wg, wgT, H_DIM, I_DIM, H_DIM, (long)H_DIM * I_DIM, (long)I_DIM * H_DIM);
  transpose_cvt<<<dim3(16, 32, 32), 256, 0, stream>>>(
      wu, wuT, H_DIM, I_DIM, H_DIM, (long)H_DIM * I_DIM, (long)I_DIM * H_DIM);
  transpose_cvt<<<dim3(32, 16, 32), 256, 0, stream>>>(
      wd, wdT, I_DIM, H_DIM, K_TOT, (long)I_DIM * H_DIM, (long)I_DIM);
  transpose_cvt<<<dim3(32, 32, 1), 256, 0, stream>>>(
      wsg, wsgT, H_DIM, IS_DIM, H_DIM, 0, 0);
  transpose_cvt<<<dim3(32, 32, 1), 256, 0, stream>>>(
      wsu, wsuT, H_DIM, IS_DIM, H_DIM, 0, 0);
  transpose_cvt<<<dim3(32, 32, 1), 256, 0, stream>>>(
      wsd, wdT + E_NUM * I_DIM, IS_DIM, H_DIM, K_TOT, 0, 0);

  // experts gate+up (dense_w folded in), then shared gate+up (weight 1)
  gate_up_kernel<<<dim3(16, 16, 32), 256, 0, stream>>>(
      xb, wgT, wuT, dense_w, hbuf, I_DIM, 0);
  gate_up_kernel<<<dim3(16, 32, 1), 256, 0, stream>>>(
      xb, wsgT, wsuT, nullptr, hbuf, IS_DIM, E_NUM * I_DIM);

  // single fused down-proj + combine + shared-down
  down_kernel<<<dim3(16, 32), 256, 0, stream>>>(hbuf, wdT, out);
}